// Round 12
// baseline (241.192 us; speedup 1.0000x reference)
//
#include <hip/hip_runtime.h>
#include <hip/hip_bf16.h>
#include <math.h>

#define NHh   8
#define EMB   256
#define HDd   32
#define NVv   6
#define SLENs 5440
#define QQ    1600
#define A_ATTN 3072   // NH*NV*NL*NP*NZ
#define A_OFF  6144

typedef _Float16 half8 __attribute__((ext_vector_type(8)));
typedef __attribute__((ext_vector_type(4))) float f32x4;

__device__ __forceinline__ unsigned short f2bf(float f) {
  __hip_bfloat16 h = __float2bfloat16(f);
  return *(unsigned short*)&h;
}
__device__ __forceinline__ unsigned short f2h(float f) {
  _Float16 h = (_Float16)f;
  return __builtin_bit_cast(unsigned short, h);
}
__device__ __forceinline__ float h2f(unsigned short u) {
  return (float)__builtin_bit_cast(_Float16, u);
}

// async global->LDS DMA, 16B per lane. LDS dest semantics: wave-uniform base
// + lane*16 (m104/m108) — caller must pass lane-ordered contiguous LDS addrs.
// HARD CONSTRAINT (rounds 2/3/9 container kills): dma16 issues must be
// followed by __syncthreads() BEFORE any LDS read / MFMA — no stage/compute
// overlap in this harness. Verified-good pattern: stage -> sync -> compute.
__device__ __forceinline__ void dma16(const unsigned short* g, unsigned short* l) {
  __builtin_amdgcn_global_load_lds(
      (const __attribute__((address_space(1))) unsigned int*)g,
      (__attribute__((address_space(3))) unsigned int*)l, 16, 0, 0);
}

// v_fma_mix_f32: acc(f32) += f16-half(dat) * f16-hi(uw).
#define FMAMIX_LO(accv, dat, uw)                                              \
  asm("v_fma_mix_f32 %0, %1, %2, %0 op_sel:[0,1,0] op_sel_hi:[1,1,0]"         \
      : "+v"(accv) : "v"(dat), "v"(uw))
#define FMAMIX_HI(accv, dat, uw)                                              \
  asm("v_fma_mix_f32 %0, %1, %2, %0 op_sel:[1,1,0] op_sel_hi:[1,1,0]"         \
      : "+v"(accv) : "v"(dat), "v"(uw))

// 16x16x32 fragment load + 16 MFMA from a pair of static 128x32 LDS tiles.
#define GEMM_COMPUTE(LAx, LBx)                                                \
  {                                                                           \
    half8 fa[4], fb[4];                                                       \
    _Pragma("unroll") for (int i = 0; i < 4; ++i) {                           \
      int ar = (wm + i * 16 + l16) * 32 + quad * 8;                           \
      int br = (wn + i * 16 + l16) * 32 + quad * 8;                           \
      fa[i] = *(const half8*)&LAx[ar];                                        \
      fb[i] = *(const half8*)&LBx[br];                                        \
    }                                                                         \
    _Pragma("unroll") for (int i = 0; i < 4; ++i)                             \
      _Pragma("unroll") for (int j = 0; j < 4; ++j)                           \
        acc[i][j] = __builtin_amdgcn_mfma_f32_16x16x32_f16(                   \
            fa[i], fb[j], acc[i][j], 0, 0, 0);                                \
  }

// 2x2 variant for 64x64 tiles ([64][32] LDS slices).
#define GEMM_COMPUTE2(LAx, LBx)                                               \
  {                                                                           \
    half8 fa[2], fb[2];                                                       \
    _Pragma("unroll") for (int i = 0; i < 2; ++i) {                           \
      int ar = (wm + i * 16 + l16) * 32 + quad * 8;                           \
      int br = (wn + i * 16 + l16) * 32 + quad * 8;                           \
      fa[i] = *(const half8*)&LAx[ar];                                        \
      fb[i] = *(const half8*)&LBx[br];                                        \
    }                                                                         \
    _Pragma("unroll") for (int i = 0; i < 2; ++i)                             \
      _Pragma("unroll") for (int j = 0; j < 2; ++j)                           \
        acc[i][j] = __builtin_amdgcn_mfma_f32_16x16x32_f16(                   \
            fa[i], fb[j], acc[i][j], 0, 0, 0);                                \
  }

// ---------------------------------------------------------------------------
// One-shot fp32 -> fp16 conversion of all GEMM operands.
// ---------------------------------------------------------------------------
__global__ __launch_bounds__(256) void split_h_kernel(
    const float* __restrict__ q, const float* __restrict__ value,
    const float* __restrict__ Woff, const float* __restrict__ Wattn,
    const float* __restrict__ Wv, const float* __restrict__ Wout,
    unsigned short* __restrict__ q16, unsigned short* __restrict__ v16,
    unsigned short* __restrict__ Wq16, unsigned short* __restrict__ Wv16,
    unsigned short* __restrict__ Wout16) {
  int i4 = blockIdx.x * 256 + threadIdx.x;   // < 2,813,952 float4-chunks
  const float* src; unsigned short* dst; int sloc; int dloc;
  if      (i4 < 102400)  { src = q;     dst = q16;    sloc = i4;           dloc = sloc; }
  else if (i4 < 2191360) { src = value; dst = v16;    sloc = i4 - 102400;  dloc = sloc; }
  else if (i4 < 2584576) { src = Woff;  dst = Wq16;   sloc = i4 - 2191360; dloc = sloc; }
  else if (i4 < 2781184) { src = Wattn; dst = Wq16;   sloc = i4 - 2584576; dloc = sloc + 393216; }
  else if (i4 < 2797568) { src = Wv;    dst = Wv16;   sloc = i4 - 2781184; dloc = sloc; }
  else                   { src = Wout;  dst = Wout16; sloc = i4 - 2797568; dloc = sloc; }
  float4 x = ((const float4*)src)[sloc];
  ushort4 hh;
  hh.x = f2h(x.x); hh.y = f2h(x.y); hh.z = f2h(x.z); hh.w = f2h(x.w);
  ((ushort4*)dst)[dloc] = hh;
}

// ---------------------------------------------------------------------------
// Merged fp16 MFMA GEMM. Round-22 change: BK = 256 = FULL K in one staging
// burst — SIXTEEN static 8 KB LDS arrays (LA0-7 / LB0-7, 128 KB total; same
// footprint as HK's verified gfx950 256-sq template). Per block: 32 dma16
// back-to-back (32/wave in flight), ONE __syncthreads drain, then 128
// MFMAs/wave + epilogue with no further stalls. K-loop eliminated.
// Rationale: drains are the measured cost — 8 drains 73.9+ µs -> 4 -> 2
// drains 59.5 µs (r10/r11); this is the endpoint (1 drain). Occupancy
// 2 -> 1 block/CU; r10->r11 proved drain-halving beats occupancy loss.
// NO stage/compute overlap (hard constraint, rounds 2/3/9).
//   blocks [0, 936):    offs/attn GEMM  (XCD-chunked, bijective 936=8*117)
//   blocks [936, 1446): val GEMM        (M=32640, N=256, permuted fp16 store)
// ---------------------------------------------------------------------------
__global__ __launch_bounds__(256) void gemm23_kernel(
    const unsigned short* __restrict__ q16, const unsigned short* __restrict__ Wq16,
    const unsigned short* __restrict__ v16, const unsigned short* __restrict__ Wv16,
    const float* __restrict__ boff, const float* __restrict__ battn,
    unsigned short* __restrict__ offs16, unsigned short* __restrict__ attn16,
    unsigned short* __restrict__ val_t) {
  __shared__ unsigned short LA0[128 * 32], LA1[128 * 32], LA2[128 * 32], LA3[128 * 32];
  __shared__ unsigned short LA4[128 * 32], LA5[128 * 32], LA6[128 * 32], LA7[128 * 32];
  __shared__ unsigned short LB0[128 * 32], LB1[128 * 32], LB2[128 * 32], LB3[128 * 32];
  __shared__ unsigned short LB4[128 * 32], LB5[128 * 32], LB6[128 * 32], LB7[128 * 32];

  const int bid = blockIdx.x;
  const unsigned short *A, *B;
  int M, bm, bn;
  bool isVal;
  if (bid < 936) {           // offs/attn, XCD-chunked: x = bid&7 owns 9 n-tiles
    int x = bid & 7, i = bid >> 3;          // i in [0,117)
    int nt = x * 9 + (i % 9), mt = i / 9;   // nt in [0,72), mt in [0,13)
    A = q16;  B = Wq16;  M = QQ;
    bn = nt * 128;  bm = mt * 128;  isVal = false;
  } else {                   // val: 2 n-tiles x 255 m-tiles
    int b2 = bid - 936;
    A = v16;  B = Wv16;  M = NVv * SLENs;
    bn = (b2 & 1) * 128;  bm = (b2 >> 1) * 128;  isVal = true;
  }
  const int K = EMB;

  const int tid = threadIdx.x;
  const int lane = tid & 63, w = tid >> 6;
  const int wm = (w & 1) * 64, wn = (w >> 1) * 64;
  const int l16 = lane & 15, quad = lane >> 4;

  const int c0 = tid, c1 = tid + 256;
  const int r0 = c0 >> 2, s0 = (c0 & 3) * 8;
  const int r1 = c1 >> 2, s1 = (c1 & 3) * 8;
  const size_t a0 = (size_t)min(bm + r0, M - 1) * K + s0;
  const size_t a1 = (size_t)min(bm + r1, M - 1) * K + s1;
  const size_t b0o = (size_t)(bn + r0) * K + s0;
  const size_t b1o = (size_t)(bn + r1) * K + s1;
  const int l0 = c0 * 8, l1 = c1 * 8;

  f32x4 acc[4][4] = {};

  // stage the ENTIRE K=256 panel pair (128 KB) in one burst
  dma16(&A[a0 +   0], &LA0[l0]);  dma16(&A[a1 +   0], &LA0[l1]);
  dma16(&A[a0 +  32], &LA1[l0]);  dma16(&A[a1 +  32], &LA1[l1]);
  dma16(&A[a0 +  64], &LA2[l0]);  dma16(&A[a1 +  64], &LA2[l1]);
  dma16(&A[a0 +  96], &LA3[l0]);  dma16(&A[a1 +  96], &LA3[l1]);
  dma16(&A[a0 + 128], &LA4[l0]);  dma16(&A[a1 + 128], &LA4[l1]);
  dma16(&A[a0 + 160], &LA5[l0]);  dma16(&A[a1 + 160], &LA5[l1]);
  dma16(&A[a0 + 192], &LA6[l0]);  dma16(&A[a1 + 192], &LA6[l1]);
  dma16(&A[a0 + 224], &LA7[l0]);  dma16(&A[a1 + 224], &LA7[l1]);
  dma16(&B[b0o +   0], &LB0[l0]); dma16(&B[b1o +   0], &LB0[l1]);
  dma16(&B[b0o +  32], &LB1[l0]); dma16(&B[b1o +  32], &LB1[l1]);
  dma16(&B[b0o +  64], &LB2[l0]); dma16(&B[b1o +  64], &LB2[l1]);
  dma16(&B[b0o +  96], &LB3[l0]); dma16(&B[b1o +  96], &LB3[l1]);
  dma16(&B[b0o + 128], &LB4[l0]); dma16(&B[b1o + 128], &LB4[l1]);
  dma16(&B[b0o + 160], &LB5[l0]); dma16(&B[b1o + 160], &LB5[l1]);
  dma16(&B[b0o + 192], &LB6[l0]); dma16(&B[b1o + 192], &LB6[l1]);
  dma16(&B[b0o + 224], &LB7[l0]); dma16(&B[b1o + 224], &LB7[l1]);
  __syncthreads();                 // the ONE drain
  GEMM_COMPUTE(LA0, LB0);
  GEMM_COMPUTE(LA1, LB1);
  GEMM_COMPUTE(LA2, LB2);
  GEMM_COMPUTE(LA3, LB3);
  GEMM_COMPUTE(LA4, LB4);
  GEMM_COMPUTE(LA5, LB5);
  GEMM_COMPUTE(LA6, LB6);
  GEMM_COMPUTE(LA7, LB7);
  // no trailing barrier: LDS is never rewritten

  // epilogue: C/D layout col(n)=lane&15, row(m)=quad*4+reg  [m89-verified]
#pragma unroll
  for (int j = 0; j < 4; ++j) {
    int n = bn + wn + j * 16 + l16;
    float bv = 0.f;
    bool dotanh = false;
    if (!isVal) {
      if (n < A_OFF) { bv = boff[n]; dotanh = true; }
      else bv = battn[n - A_OFF];
    }
#pragma unroll
    for (int i = 0; i < 4; ++i) {
      int mbase = bm + wm + i * 16 + quad * 4;
#pragma unroll
      for (int reg = 0; reg < 4; ++reg) {
        int m = mbase + reg;
        if (m >= M) continue;
        float c = acc[i][j][reg] + bv;
        if (isVal) {   // fp16 permuted store: m=(v*SLEN+s), n=(h*32+d)
          int vv = m / SLENs;
          int s = m - vv * SLENs;
          int hh2 = n >> 5, dd = n & 31;
          val_t[((size_t)(vv * 8 + hh2) * SLENs + s) * 32 + dd] = f2h(c);
        } else if (dotanh) {
          float t = __expf(2.f * c);
          c = 1.f - 2.f / (t + 1.f);
          offs16[(size_t)m * A_OFF + n] = f2h(c);
        } else {
          attn16[(size_t)m * A_ATTN + (n - A_OFF)] = f2h(c);
        }
      }
    }
  }
}

// ---------------------------------------------------------------------------
// fp16 MFMA GEMM, MODE 0 only (final out = out_pre @ Wout.T, f32 store).
// Round-21 verified: 64x64 tiles (100 blocks), BK=128 four static slice
// pairs (32 KB LDS), two drains per block.
// ---------------------------------------------------------------------------
__global__ __launch_bounds__(256) void gemmh0_kernel(
    const unsigned short* __restrict__ A, const unsigned short* __restrict__ B,
    float* __restrict__ C, int M, int N, int K) {
  __shared__ unsigned short LA0[64 * 32], LA1[64 * 32], LA2[64 * 32], LA3[64 * 32];
  __shared__ unsigned short LB0[64 * 32], LB1[64 * 32], LB2[64 * 32], LB3[64 * 32];

  const int tid = threadIdx.x;
  const int bm = blockIdx.y * 64, bn = blockIdx.x * 64;
  const int lane = tid & 63, w = tid >> 6;
  const int wm = (w & 1) * 32, wn = (w >> 1) * 32;
  const int l16 = lane & 15, quad = lane >> 4;

  // one dma16 round covers a full 64x32 slice: 256 chunks of 8 halfs
  const int r0 = tid >> 2, s0 = (tid & 3) * 8;
  const size_t a0 = (size_t)min(bm + r0, M - 1) * K + s0;
  const size_t b0o = (size_t)(bn + r0) * K + s0;
  const int l0 = tid * 8;

  f32x4 acc[2][2] = {};

#pragma unroll
  for (int k0 = 0; k0 < K; k0 += 128) {
    dma16(&A[a0 + k0],       &LA0[l0]);
    dma16(&A[a0 + k0 + 32],  &LA1[l0]);
    dma16(&A[a0 + k0 + 64],  &LA2[l0]);
    dma16(&A[a0 + k0 + 96],  &LA3[l0]);
    dma16(&B[b0o + k0],      &LB0[l0]);
    dma16(&B[b0o + k0 + 32], &LB1[l0]);
    dma16(&B[b0o + k0 + 64], &LB2[l0]);
    dma16(&B[b0o + k0 + 96], &LB3[l0]);
    __syncthreads();
    GEMM_COMPUTE2(LA0, LB0);
    GEMM_COMPUTE2(LA1, LB1);
    GEMM_COMPUTE2(LA2, LB2);
    GEMM_COMPUTE2(LA3, LB3);
    __syncthreads();
  }

#pragma unroll
  for (int j = 0; j < 2; ++j) {
    int n = bn + wn + j * 16 + l16;
#pragma unroll
    for (int i = 0; i < 2; ++i) {
      int mbase = bm + wm + i * 16 + quad * 4;
#pragma unroll
      for (int reg = 0; reg < 4; ++reg) {
        int m = mbase + reg;
        if (m >= M) continue;
        C[(size_t)m * N + n] = acc[i][j][reg];
      }
    }
  }
}

// ---------------------------------------------------------------------------
// Fused softmax + record build + sampling — VERIFIED round-7 form
// (256 threads, 4 waves, Lrec[4][384], grid QQ*NH/4). Declared done at
// ~60 µs: occupancy levers null (rounds 1/8), MLP levers null (round 6),
// VALU lever captured (round 5). L1 line-rate floor ~32 µs + issue stream.
// ---------------------------------------------------------------------------
__global__ __launch_bounds__(256) void sample_kernel(
    const float* __restrict__ ref, const unsigned short* __restrict__ offs16,
    const unsigned short* __restrict__ attn16,
    const unsigned short* __restrict__ val_t,
    unsigned short* __restrict__ op16) {
  __shared__ int4 Lrec[4][384];

  const int h   = blockIdx.x & 7;
  const int qt  = blockIdx.x >> 3;
  const int wid = threadIdx.x >> 6;
  const int lane = threadIdx.x & 63;
  const int q   = qt * 4 + wid;
  const int row = q * 8 + h;

  {
    const unsigned short* ap = attn16 + (size_t)row * 384;
    float vals[6];
    float mx = -1e30f;
#pragma unroll
    for (int i = 0; i < 6; ++i) { vals[i] = h2f(ap[lane + i * 64]); mx = fmaxf(mx, vals[i]); }
#pragma unroll
    for (int o = 32; o > 0; o >>= 1) mx = fmaxf(mx, __shfl_xor(mx, o, 64));
    float s = 0.f;
#pragma unroll
    for (int i = 0; i < 6; ++i) { vals[i] = __expf(vals[i] - mx); s += vals[i]; }
#pragma unroll
    for (int o = 32; o > 0; o >>= 1) s += __shfl_xor(s, o, 64);
    const float inv = 1.0f / s;

    const int l = (lane >> 4) & 3;
    const int z = lane & 3;
    const int Wl = 64 >> l;
    const int start = (l == 0) ? 0 : (l == 1 ? 4096 : (l == 2 ? 5120 : 5376));
    const float sc = 0.5f * (float)(Wl - 1);
    const unsigned int* op = (const unsigned int*)offs16 + (size_t)row * 384;
    const float* rq = ref + (size_t)q * (NVv * 4 * 4 * 2);

#pragma unroll 1
    for (int v = 0; v < 6; ++v) {
      int j = v * 64 + lane;
      float w = vals[v] * inv;
      unsigned int oxy = op[j];
      float ox = h2f((unsigned short)(oxy & 0xFFFF));
      float oy = h2f((unsigned short)(oxy >> 16));
      const float* rp = rq + ((v * 4 + l) * 4 + z) * 2;
      float rx = rp[0], ry = rp[1];
      float x = fminf(1.f, fmaxf(-1.f, rx + ox));
      float y = fminf(1.f, fmaxf(-1.f, ry + oy));
      float xp = (x + 1.f) * sc, yp = (y + 1.f) * sc;
      float x0f = floorf(xp), y0f = floorf(yp);
      int x0 = (int)x0f, y0 = (int)y0f;
      float wx = xp - x0f, wy = yp - y0f;
      unsigned i00 = (unsigned)(start + y0 * Wl + x0);
      unsigned dxe = (x0 + 1 < Wl) ? 1u : 0u;
      unsigned dye = (y0 + 1 < Wl) ? (unsigned)Wl : 0u;
      unsigned i10 = i00 + dye;
      float wxw = wx * w, wmx = w - wxw;
      float w01 = wxw * (1.f - wy), w11 = wxw * wy;
      float w00 = wmx * (1.f - wy), w10 = wmx * wy;
      Lrec[wid][j] = make_int4(
          (int)(i00         | ((unsigned)f2h(w00) << 16)),
          (int)((i00 + dxe) | ((unsigned)f2h(w01) << 16)),
          (int)(i10         | ((unsigned)f2h(w10) << 16)),
          (int)((i10 + dxe) | ((unsigned)f2h(w11) << 16)));
    }
  }
  // no __syncthreads: each wave consumes only its own Lrec slice

  const int cb  = (lane >> 2) & 3;
  const int e16 = (lane & 3) << 4;
  const int r   = lane >> 4;

  const unsigned* Lw = (const unsigned*)&Lrec[wid][0];

  float acc[8] = {};

#pragma unroll 1
  for (int v = 0; v < 6; ++v) {
    const char* sb = (const char*)val_t + (size_t)(v * 8 + h) * (SLENs * 64);
    const int rbase = v * 64 + r;
#pragma unroll 8
    for (int t = 0; t < 16; ++t) {
      int ri = rbase + t * 4;
      unsigned u = Lw[ri * 4 + cb];
      int voff = ((int)(u & 0xFFFFu) << 6) + e16;
      uint4 d = *(const uint4*)(sb + voff);
      FMAMIX_LO(acc[0], d.x, u);  FMAMIX_HI(acc[1], d.x, u);
      FMAMIX_LO(acc[2], d.y, u);  FMAMIX_HI(acc[3], d.y, u);
      FMAMIX_LO(acc[4], d.z, u);  FMAMIX_HI(acc[5], d.z, u);
      FMAMIX_LO(acc[6], d.w, u);  FMAMIX_HI(acc[7], d.w, u);
    }
  }

#pragma unroll
  for (int m = 4; m <= 32; m <<= 1)
#pragma unroll
    for (int j = 0; j < 8; ++j) acc[j] += __shfl_xor(acc[j], m, 64);

  if (lane < 4) {
    int off = q * EMB + h * 32 + lane * 8;
    ushort4 h0, h1;
    h0.x = f2h(acc[0]); h0.y = f2h(acc[1]); h0.z = f2h(acc[2]); h0.w = f2h(acc[3]);
    h1.x = f2h(acc[4]); h1.y = f2h(acc[5]); h1.z = f2h(acc[6]); h1.w = f2h(acc[7]);
    *(ushort4*)&op16[off] = h0;  *(ushort4*)&op16[off + 4] = h1;
  }
}

// ---------------------------------------------------------------------------
extern "C" void kernel_launch(void* const* d_in, const int* in_sizes, int n_in,
                              void* d_out, int out_size, void* d_ws, size_t ws_size,
                              hipStream_t stream) {
  const float* queries    = (const float*)d_in[0];
  const float* ref_points = (const float*)d_in[1];
  const float* value      = (const float*)d_in[2];
  const float* Wv    = (const float*)d_in[4];
  const float* Woff  = (const float*)d_in[5];
  const float* boff  = (const float*)d_in[6];
  const float* Wattn = (const float*)d_in[7];
  const float* battn = (const float*)d_in[8];
  const float* Wout  = (const float*)d_in[9];
  float* out = (float*)d_out;

  // ws layout, byte offsets — total 69.5 MB.
  char* W = (char*)d_ws;
  unsigned short* offs16 = (unsigned short*)(W + 0);         // 19,660,800
  unsigned short* attn16 = (unsigned short*)(W + 19660800);  //  9,830,400
  unsigned short* val_t  = (unsigned short*)(W + 29491200);  // 16,711,680 (fp16)
  unsigned short* q16    = (unsigned short*)(W + 46202880);  //    819,200
  unsigned short* v16    = (unsigned short*)(W + 47022080);  // 16,711,680
  unsigned short* Wq16   = (unsigned short*)(W + 63733760);  //  4,718,592 (Woff||Wattn)
  unsigned short* Wv16   = (unsigned short*)(W + 68452352);  //    131,072
  unsigned short* Wout16 = (unsigned short*)(W + 68583424);  //    131,072
  unsigned short* op16   = (unsigned short*)(W + 68714496);  //    819,200

  dim3 blk(256);

  // 1. convert all GEMM operands to fp16 (single-pass)
  split_h_kernel<<<10992, blk, 0, stream>>>(
      queries, value, Woff, Wattn, Wv, Wout, q16, v16, Wq16, Wv16, Wout16);
  // 2. merged offs/attn GEMM (936 blocks, XCD-chunked) + val GEMM (510 blocks)
  gemm23_kernel<<<1446, blk, 0, stream>>>(
      q16, Wq16, v16, Wv16, boff, battn, offs16, attn16, val_t);
  // 3. fused softmax + record build + sampling -> out_pre fp16
  sample_kernel<<<QQ * NHh / 4, blk, 0, stream>>>(
      ref_points, offs16, attn16, val_t, op16);
  // 4. out = out_pre @ Wout.T (fp16 in, fp32 out) — 64x64 tiles, 100 blocks
  gemmh0_kernel<<<dim3(EMB / 64, QQ / 64), blk, 0, stream>>>(
      op16, Wout16, out, QQ, EMB, EMB);
}

// Round 13
// 223.177 us; speedup vs baseline: 1.0807x; 1.0807x over previous
//
#include <hip/hip_runtime.h>
#include <hip/hip_bf16.h>
#include <math.h>

#define NHh   8
#define EMB   256
#define HDd   32
#define NVv   6
#define SLENs 5440
#define QQ    1600
#define A_ATTN 3072   // NH*NV*NL*NP*NZ
#define A_OFF  6144

typedef _Float16 half8 __attribute__((ext_vector_type(8)));
typedef __attribute__((ext_vector_type(4))) float f32x4;

__device__ __forceinline__ unsigned short f2bf(float f) {
  __hip_bfloat16 h = __float2bfloat16(f);
  return *(unsigned short*)&h;
}
__device__ __forceinline__ unsigned short f2h(float f) {
  _Float16 h = (_Float16)f;
  return __builtin_bit_cast(unsigned short, h);
}
__device__ __forceinline__ float h2f(unsigned short u) {
  return (float)__builtin_bit_cast(_Float16, u);
}

// async global->LDS DMA, 16B per lane. LDS dest semantics: wave-uniform base
// + lane*16 (m104/m108) — caller must pass lane-ordered contiguous LDS addrs.
// HARD CONSTRAINT (rounds 2/3/9 container kills): dma16 issues must be
// followed by __syncthreads() BEFORE any LDS read / MFMA — no stage/compute
// overlap in this harness. Verified-good pattern: stage -> sync -> compute.
__device__ __forceinline__ void dma16(const unsigned short* g, unsigned short* l) {
  __builtin_amdgcn_global_load_lds(
      (const __attribute__((address_space(1))) unsigned int*)g,
      (__attribute__((address_space(3))) unsigned int*)l, 16, 0, 0);
}

// v_fma_mix_f32: acc(f32) += f16-half(dat) * f16-hi(uw).
#define FMAMIX_LO(accv, dat, uw)                                              \
  asm("v_fma_mix_f32 %0, %1, %2, %0 op_sel:[0,1,0] op_sel_hi:[1,1,0]"         \
      : "+v"(accv) : "v"(dat), "v"(uw))
#define FMAMIX_HI(accv, dat, uw)                                              \
  asm("v_fma_mix_f32 %0, %1, %2, %0 op_sel:[1,1,0] op_sel_hi:[1,1,0]"         \
      : "+v"(accv) : "v"(dat), "v"(uw))

// 2x2 variant for 64x64 tiles ([64][32] LDS slices) — used by gemmh0.
#define GEMM_COMPUTE2(LAx, LBx)                                               \
  {                                                                           \
    half8 fa[2], fb[2];                                                       \
    _Pragma("unroll") for (int i = 0; i < 2; ++i) {                           \
      int ar = (wm + i * 16 + l16) * 32 + quad * 8;                           \
      int br = (wn + i * 16 + l16) * 32 + quad * 8;                           \
      fa[i] = *(const half8*)&LAx[ar];                                        \
      fb[i] = *(const half8*)&LBx[br];                                        \
    }                                                                         \
    _Pragma("unroll") for (int i = 0; i < 2; ++i)                             \
      _Pragma("unroll") for (int j = 0; j < 2; ++j)                           \
        acc[i][j] = __builtin_amdgcn_mfma_f32_16x16x32_f16(                   \
            fa[i], fb[j], acc[i][j], 0, 0, 0);                                \
  }

// ---------------------------------------------------------------------------
// One-shot fp32 -> fp16 conversion of all GEMM operands.
// ---------------------------------------------------------------------------
__global__ __launch_bounds__(256) void split_h_kernel(
    const float* __restrict__ q, const float* __restrict__ value,
    const float* __restrict__ Woff, const float* __restrict__ Wattn,
    const float* __restrict__ Wv, const float* __restrict__ Wout,
    unsigned short* __restrict__ q16, unsigned short* __restrict__ v16,
    unsigned short* __restrict__ Wq16, unsigned short* __restrict__ Wv16,
    unsigned short* __restrict__ Wout16) {
  int i4 = blockIdx.x * 256 + threadIdx.x;   // < 2,813,952 float4-chunks
  const float* src; unsigned short* dst; int sloc; int dloc;
  if      (i4 < 102400)  { src = q;     dst = q16;    sloc = i4;           dloc = sloc; }
  else if (i4 < 2191360) { src = value; dst = v16;    sloc = i4 - 102400;  dloc = sloc; }
  else if (i4 < 2584576) { src = Woff;  dst = Wq16;   sloc = i4 - 2191360; dloc = sloc; }
  else if (i4 < 2781184) { src = Wattn; dst = Wq16;   sloc = i4 - 2584576; dloc = sloc + 393216; }
  else if (i4 < 2797568) { src = Wv;    dst = Wv16;   sloc = i4 - 2781184; dloc = sloc; }
  else                   { src = Wout;  dst = Wout16; sloc = i4 - 2797568; dloc = sloc; }
  float4 x = ((const float4*)src)[sloc];
  ushort4 hh;
  hh.x = f2h(x.x); hh.y = f2h(x.y); hh.z = f2h(x.z); hh.w = f2h(x.w);
  ((ushort4*)dst)[dloc] = hh;
}

// ---------------------------------------------------------------------------
// Merged fp16 MFMA GEMM. Round-23 change: NO-LDS direct-fragment GEMM.
// K=256 is tiny and K-major: every MFMA fragment is a 16B/lane contiguous
// global load (same lane->data mapping as the old LDS read — bit-identical
// results). Each wave loads its own A/B fragments global->VGPR and feeds
// MFMA directly: ZERO barriers, ZERO vmcnt(0) drains, ZERO bank conflicts,
// ZERO LDS. Cost: 2x fragment re-read across waves (~370 MB from L2/L3,
// ~11 µs of a 34.5 TB/s ceiling — cheap). With no barriers the compiler is
// free to software-pipeline loads ahead of MFMAs, and ~4 blocks/CU of TLP
// covers L2/L3 latency.
// Rationale: BK ladder exhausted (8 drains=74, 2=59.5, 1=89 µs); stall is
// the stage->drain structure itself; pipelining is poisoned (r2/3/9).
//   blocks [0, 936):    offs/attn GEMM  (XCD-chunked, bijective 936=8*117)
//   blocks [936, 1446): val GEMM        (M=32640, N=256, permuted fp16 store)
// ---------------------------------------------------------------------------
__global__ __launch_bounds__(256) void gemm23_kernel(
    const unsigned short* __restrict__ q16, const unsigned short* __restrict__ Wq16,
    const unsigned short* __restrict__ v16, const unsigned short* __restrict__ Wv16,
    const float* __restrict__ boff, const float* __restrict__ battn,
    unsigned short* __restrict__ offs16, unsigned short* __restrict__ attn16,
    unsigned short* __restrict__ val_t) {
  const int bid = blockIdx.x;
  const unsigned short *A, *B;
  int M, bm, bn;
  bool isVal;
  if (bid < 936) {           // offs/attn, XCD-chunked: x = bid&7 owns 9 n-tiles
    int x = bid & 7, i = bid >> 3;          // i in [0,117)
    int nt = x * 9 + (i % 9), mt = i / 9;   // nt in [0,72), mt in [0,13)
    A = q16;  B = Wq16;  M = QQ;
    bn = nt * 128;  bm = mt * 128;  isVal = false;
  } else {                   // val: 2 n-tiles x 255 m-tiles
    int b2 = bid - 936;
    A = v16;  B = Wv16;  M = NVv * SLENs;
    bn = (b2 & 1) * 128;  bm = (b2 >> 1) * 128;  isVal = true;
  }
  const int K = EMB;

  const int tid = threadIdx.x;
  const int lane = tid & 63, w = tid >> 6;
  const int wm = (w & 1) * 64, wn = (w >> 1) * 64;
  const int l16 = lane & 15, quad = lane >> 4;

  // per-lane fragment base pointers (16B-aligned: row*512B + quad*16B)
  const unsigned short* Arow[4];
  const unsigned short* Brow[4];
#pragma unroll
  for (int i = 0; i < 4; ++i)
    Arow[i] = A + (size_t)min(bm + wm + i * 16 + l16, M - 1) * K + quad * 8;
#pragma unroll
  for (int j = 0; j < 4; ++j)
    Brow[j] = B + (size_t)(bn + wn + j * 16 + l16) * K + quad * 8;

  f32x4 acc[4][4] = {};

#pragma unroll
  for (int k0 = 0; k0 < 256; k0 += 32) {
    half8 fa[4], fb[4];
#pragma unroll
    for (int i = 0; i < 4; ++i) fa[i] = *(const half8*)(Arow[i] + k0);
#pragma unroll
    for (int j = 0; j < 4; ++j) fb[j] = *(const half8*)(Brow[j] + k0);
#pragma unroll
    for (int i = 0; i < 4; ++i)
#pragma unroll
      for (int j = 0; j < 4; ++j)
        acc[i][j] = __builtin_amdgcn_mfma_f32_16x16x32_f16(fa[i], fb[j], acc[i][j], 0, 0, 0);
  }

  // epilogue: C/D layout col(n)=lane&15, row(m)=quad*4+reg  [m89-verified]
#pragma unroll
  for (int j = 0; j < 4; ++j) {
    int n = bn + wn + j * 16 + l16;
    float bv = 0.f;
    bool dotanh = false;
    if (!isVal) {
      if (n < A_OFF) { bv = boff[n]; dotanh = true; }
      else bv = battn[n - A_OFF];
    }
#pragma unroll
    for (int i = 0; i < 4; ++i) {
      int mbase = bm + wm + i * 16 + quad * 4;
#pragma unroll
      for (int reg = 0; reg < 4; ++reg) {
        int m = mbase + reg;
        if (m >= M) continue;
        float c = acc[i][j][reg] + bv;
        if (isVal) {   // fp16 permuted store: m=(v*SLEN+s), n=(h*32+d)
          int vv = m / SLENs;
          int s = m - vv * SLENs;
          int hh2 = n >> 5, dd = n & 31;
          val_t[((size_t)(vv * 8 + hh2) * SLENs + s) * 32 + dd] = f2h(c);
        } else if (dotanh) {
          float t = __expf(2.f * c);
          c = 1.f - 2.f / (t + 1.f);
          offs16[(size_t)m * A_OFF + n] = f2h(c);
        } else {
          attn16[(size_t)m * A_ATTN + (n - A_OFF)] = f2h(c);
        }
      }
    }
  }
}

// ---------------------------------------------------------------------------
// fp16 MFMA GEMM, MODE 0 only (final out = out_pre @ Wout.T, f32 store).
// Round-21/VERIFIED r11 form: 64x64 tiles (100 blocks), BK=128 four static
// slice pairs (32 KB LDS), two drains per block. stage->sync->compute only.
// ---------------------------------------------------------------------------
__global__ __launch_bounds__(256) void gemmh0_kernel(
    const unsigned short* __restrict__ A, const unsigned short* __restrict__ B,
    float* __restrict__ C, int M, int N, int K) {
  __shared__ unsigned short LA0[64 * 32], LA1[64 * 32], LA2[64 * 32], LA3[64 * 32];
  __shared__ unsigned short LB0[64 * 32], LB1[64 * 32], LB2[64 * 32], LB3[64 * 32];

  const int tid = threadIdx.x;
  const int bm = blockIdx.y * 64, bn = blockIdx.x * 64;
  const int lane = tid & 63, w = tid >> 6;
  const int wm = (w & 1) * 32, wn = (w >> 1) * 32;
  const int l16 = lane & 15, quad = lane >> 4;

  // one dma16 round covers a full 64x32 slice: 256 chunks of 8 halfs
  const int r0 = tid >> 2, s0 = (tid & 3) * 8;
  const size_t a0 = (size_t)min(bm + r0, M - 1) * K + s0;
  const size_t b0o = (size_t)(bn + r0) * K + s0;
  const int l0 = tid * 8;

  f32x4 acc[2][2] = {};

#pragma unroll
  for (int k0 = 0; k0 < K; k0 += 128) {
    dma16(&A[a0 + k0],       &LA0[l0]);
    dma16(&A[a0 + k0 + 32],  &LA1[l0]);
    dma16(&A[a0 + k0 + 64],  &LA2[l0]);
    dma16(&A[a0 + k0 + 96],  &LA3[l0]);
    dma16(&B[b0o + k0],      &LB0[l0]);
    dma16(&B[b0o + k0 + 32], &LB1[l0]);
    dma16(&B[b0o + k0 + 64], &LB2[l0]);
    dma16(&B[b0o + k0 + 96], &LB3[l0]);
    __syncthreads();
    GEMM_COMPUTE2(LA0, LB0);
    GEMM_COMPUTE2(LA1, LB1);
    GEMM_COMPUTE2(LA2, LB2);
    GEMM_COMPUTE2(LA3, LB3);
    __syncthreads();
  }

#pragma unroll
  for (int j = 0; j < 2; ++j) {
    int n = bn + wn + j * 16 + l16;
#pragma unroll
    for (int i = 0; i < 2; ++i) {
      int mbase = bm + wm + i * 16 + quad * 4;
#pragma unroll
      for (int reg = 0; reg < 4; ++reg) {
        int m = mbase + reg;
        if (m >= M) continue;
        C[(size_t)m * N + n] = acc[i][j][reg];
      }
    }
  }
}

// ---------------------------------------------------------------------------
// Fused softmax + record build + sampling — VERIFIED round-7 form
// (256 threads, 4 waves, Lrec[4][384], grid QQ*NH/4). Declared done at
// ~60 µs: occupancy levers null (rounds 1/8), MLP levers null (round 6),
// VALU lever captured (round 5). L1 line-rate floor ~32 µs + issue stream.
// ---------------------------------------------------------------------------
__global__ __launch_bounds__(256) void sample_kernel(
    const float* __restrict__ ref, const unsigned short* __restrict__ offs16,
    const unsigned short* __restrict__ attn16,
    const unsigned short* __restrict__ val_t,
    unsigned short* __restrict__ op16) {
  __shared__ int4 Lrec[4][384];

  const int h   = blockIdx.x & 7;
  const int qt  = blockIdx.x >> 3;
  const int wid = threadIdx.x >> 6;
  const int lane = threadIdx.x & 63;
  const int q   = qt * 4 + wid;
  const int row = q * 8 + h;

  {
    const unsigned short* ap = attn16 + (size_t)row * 384;
    float vals[6];
    float mx = -1e30f;
#pragma unroll
    for (int i = 0; i < 6; ++i) { vals[i] = h2f(ap[lane + i * 64]); mx = fmaxf(mx, vals[i]); }
#pragma unroll
    for (int o = 32; o > 0; o >>= 1) mx = fmaxf(mx, __shfl_xor(mx, o, 64));
    float s = 0.f;
#pragma unroll
    for (int i = 0; i < 6; ++i) { vals[i] = __expf(vals[i] - mx); s += vals[i]; }
#pragma unroll
    for (int o = 32; o > 0; o >>= 1) s += __shfl_xor(s, o, 64);
    const float inv = 1.0f / s;

    const int l = (lane >> 4) & 3;
    const int z = lane & 3;
    const int Wl = 64 >> l;
    const int start = (l == 0) ? 0 : (l == 1 ? 4096 : (l == 2 ? 5120 : 5376));
    const float sc = 0.5f * (float)(Wl - 1);
    const unsigned int* op = (const unsigned int*)offs16 + (size_t)row * 384;
    const float* rq = ref + (size_t)q * (NVv * 4 * 4 * 2);

#pragma unroll 1
    for (int v = 0; v < 6; ++v) {
      int j = v * 64 + lane;
      float w = vals[v] * inv;
      unsigned int oxy = op[j];
      float ox = h2f((unsigned short)(oxy & 0xFFFF));
      float oy = h2f((unsigned short)(oxy >> 16));
      const float* rp = rq + ((v * 4 + l) * 4 + z) * 2;
      float rx = rp[0], ry = rp[1];
      float x = fminf(1.f, fmaxf(-1.f, rx + ox));
      float y = fminf(1.f, fmaxf(-1.f, ry + oy));
      float xp = (x + 1.f) * sc, yp = (y + 1.f) * sc;
      float x0f = floorf(xp), y0f = floorf(yp);
      int x0 = (int)x0f, y0 = (int)y0f;
      float wx = xp - x0f, wy = yp - y0f;
      unsigned i00 = (unsigned)(start + y0 * Wl + x0);
      unsigned dxe = (x0 + 1 < Wl) ? 1u : 0u;
      unsigned dye = (y0 + 1 < Wl) ? (unsigned)Wl : 0u;
      unsigned i10 = i00 + dye;
      float wxw = wx * w, wmx = w - wxw;
      float w01 = wxw * (1.f - wy), w11 = wxw * wy;
      float w00 = wmx * (1.f - wy), w10 = wmx * wy;
      Lrec[wid][j] = make_int4(
          (int)(i00         | ((unsigned)f2h(w00) << 16)),
          (int)((i00 + dxe) | ((unsigned)f2h(w01) << 16)),
          (int)(i10         | ((unsigned)f2h(w10) << 16)),
          (int)((i10 + dxe) | ((unsigned)f2h(w11) << 16)));
    }
  }
  // no __syncthreads: each wave consumes only its own Lrec slice

  const int cb  = (lane >> 2) & 3;
  const int e16 = (lane & 3) << 4;
  const int r   = lane >> 4;

  const unsigned* Lw = (const unsigned*)&Lrec[wid][0];

  float acc[8] = {};

#pragma unroll 1
  for (int v = 0; v < 6; ++v) {
    const char* sb = (const char*)val_t + (size_t)(v * 8 + h) * (SLENs * 64);
    const int rbase = v * 64 + r;
#pragma unroll 8
    for (int t = 0; t < 16; ++t) {
      int ri = rbase + t * 4;
      unsigned u = Lw[ri * 4 + cb];
      int voff = ((int)(u & 0xFFFFu) << 6) + e16;
      uint4 d = *(const uint4*)(sb + voff);
      FMAMIX_LO(acc[0], d.x, u);  FMAMIX_HI(acc[1], d.x, u);
      FMAMIX_LO(acc[2], d.y, u);  FMAMIX_HI(acc[3], d.y, u);
      FMAMIX_LO(acc[4], d.z, u);  FMAMIX_HI(acc[5], d.z, u);
      FMAMIX_LO(acc[6], d.w, u);  FMAMIX_HI(acc[7], d.w, u);
    }
  }

#pragma unroll
  for (int m = 4; m <= 32; m <<= 1)
#pragma unroll
    for (int j = 0; j < 8; ++j) acc[j] += __shfl_xor(acc[j], m, 64);

  if (lane < 4) {
    int off = q * EMB + h * 32 + lane * 8;
    ushort4 h0, h1;
    h0.x = f2h(acc[0]); h0.y = f2h(acc[1]); h0.z = f2h(acc[2]); h0.w = f2h(acc[3]);
    h1.x = f2h(acc[4]); h1.y = f2h(acc[5]); h1.z = f2h(acc[6]); h1.w = f2h(acc[7]);
    *(ushort4*)&op16[off] = h0;  *(ushort4*)&op16[off + 4] = h1;
  }
}

// ---------------------------------------------------------------------------
extern "C" void kernel_launch(void* const* d_in, const int* in_sizes, int n_in,
                              void* d_out, int out_size, void* d_ws, size_t ws_size,
                              hipStream_t stream) {
  const float* queries    = (const float*)d_in[0];
  const float* ref_points = (const float*)d_in[1];
  const float* value      = (const float*)d_in[2];
  const float* Wv    = (const float*)d_in[4];
  const float* Woff  = (const float*)d_in[5];
  const float* boff  = (const float*)d_in[6];
  const float* Wattn = (const float*)d_in[7];
  const float* battn = (const float*)d_in[8];
  const float* Wout  = (const float*)d_in[9];
  float* out = (float*)d_out;

  // ws layout, byte offsets — total 69.5 MB.
  char* W = (char*)d_ws;
  unsigned short* offs16 = (unsigned short*)(W + 0);         // 19,660,800
  unsigned short* attn16 = (unsigned short*)(W + 19660800);  //  9,830,400
  unsigned short* val_t  = (unsigned short*)(W + 29491200);  // 16,711,680 (fp16)
  unsigned short* q16    = (unsigned short*)(W + 46202880);  //    819,200
  unsigned short* v16    = (unsigned short*)(W + 47022080);  // 16,711,680
  unsigned short* Wq16   = (unsigned short*)(W + 63733760);  //  4,718,592 (Woff||Wattn)
  unsigned short* Wv16   = (unsigned short*)(W + 68452352);  //    131,072
  unsigned short* Wout16 = (unsigned short*)(W + 68583424);  //    131,072
  unsigned short* op16   = (unsigned short*)(W + 68714496);  //    819,200

  dim3 blk(256);

  // 1. convert all GEMM operands to fp16 (single-pass)
  split_h_kernel<<<10992, blk, 0, stream>>>(
      queries, value, Woff, Wattn, Wv, Wout, q16, v16, Wq16, Wv16, Wout16);
  // 2. merged offs/attn GEMM (936 blocks, XCD-chunked) + val GEMM (510 blocks)
  gemm23_kernel<<<1446, blk, 0, stream>>>(
      q16, Wq16, v16, Wv16, boff, battn, offs16, attn16, val_t);
  // 3. fused softmax + record build + sampling -> out_pre fp16
  sample_kernel<<<QQ * NHh / 4, blk, 0, stream>>>(
      ref_points, offs16, attn16, val_t, op16);
  // 4. out = out_pre @ Wout.T (fp16 in, fp32 out) — 64x64 tiles, 100 blocks
  gemmh0_kernel<<<dim3(EMB / 64, QQ / 64), blk, 0, stream>>>(
      op16, Wout16, out, QQ, EMB, EMB);
}

// Round 14
// 197.204 us; speedup vs baseline: 1.2231x; 1.1317x over previous
//
#include <hip/hip_runtime.h>
#include <hip/hip_bf16.h>
#include <math.h>

#define NHh   8
#define EMB   256
#define HDd   32
#define NVv   6
#define SLENs 5440
#define QQ    1600
#define A_ATTN 3072   // NH*NV*NL*NP*NZ
#define A_OFF  6144

typedef _Float16 half8 __attribute__((ext_vector_type(8)));
typedef __attribute__((ext_vector_type(4))) float f32x4;

__device__ __forceinline__ unsigned short f2bf(float f) {
  __hip_bfloat16 h = __float2bfloat16(f);
  return *(unsigned short*)&h;
}
__device__ __forceinline__ unsigned short f2h(float f) {
  _Float16 h = (_Float16)f;
  return __builtin_bit_cast(unsigned short, h);
}
__device__ __forceinline__ float h2f(unsigned short u) {
  return (float)__builtin_bit_cast(_Float16, u);
}

// async global->LDS DMA, 16B per lane. LDS dest semantics: wave-uniform base
// + lane*16 (m104/m108) — caller must pass lane-ordered contiguous LDS addrs.
// HARD CONSTRAINT (rounds 2/3/9 container kills): dma16 issues must be
// followed by __syncthreads() BEFORE any LDS read / MFMA — no stage/compute
// overlap in this harness. Verified-good pattern: stage -> sync -> compute.
__device__ __forceinline__ void dma16(const unsigned short* g, unsigned short* l) {
  __builtin_amdgcn_global_load_lds(
      (const __attribute__((address_space(1))) unsigned int*)g,
      (__attribute__((address_space(3))) unsigned int*)l, 16, 0, 0);
}

// v_fma_mix_f32: acc(f32) += f16-half(dat) * f16-hi(uw).
#define FMAMIX_LO(accv, dat, uw)                                              \
  asm("v_fma_mix_f32 %0, %1, %2, %0 op_sel:[0,1,0] op_sel_hi:[1,1,0]"         \
      : "+v"(accv) : "v"(dat), "v"(uw))
#define FMAMIX_HI(accv, dat, uw)                                              \
  asm("v_fma_mix_f32 %0, %1, %2, %0 op_sel:[1,1,0] op_sel_hi:[1,1,0]"         \
      : "+v"(accv) : "v"(dat), "v"(uw))

// 2x2 fragment load + 4 MFMA from a pair of static 64x32 LDS slices.
// (The verified gemmh0 compute macro — now used by BOTH GEMM kernels.)
#define GEMM_COMPUTE2(LAx, LBx)                                               \
  {                                                                           \
    half8 fa[2], fb[2];                                                       \
    _Pragma("unroll") for (int i = 0; i < 2; ++i) {                           \
      int ar = (wm + i * 16 + l16) * 32 + quad * 8;                           \
      int br = (wn + i * 16 + l16) * 32 + quad * 8;                           \
      fa[i] = *(const half8*)&LAx[ar];                                        \
      fb[i] = *(const half8*)&LBx[br];                                        \
    }                                                                         \
    _Pragma("unroll") for (int i = 0; i < 2; ++i)                             \
      _Pragma("unroll") for (int j = 0; j < 2; ++j)                           \
        acc[i][j] = __builtin_amdgcn_mfma_f32_16x16x32_f16(                   \
            fa[i], fb[j], acc[i][j], 0, 0, 0);                                \
  }

// ---------------------------------------------------------------------------
// One-shot fp32 -> fp16 conversion of all GEMM operands.
// ---------------------------------------------------------------------------
__global__ __launch_bounds__(256) void split_h_kernel(
    const float* __restrict__ q, const float* __restrict__ value,
    const float* __restrict__ Woff, const float* __restrict__ Wattn,
    const float* __restrict__ Wv, const float* __restrict__ Wout,
    unsigned short* __restrict__ q16, unsigned short* __restrict__ v16,
    unsigned short* __restrict__ Wq16, unsigned short* __restrict__ Wv16,
    unsigned short* __restrict__ Wout16) {
  int i4 = blockIdx.x * 256 + threadIdx.x;   // < 2,813,952 float4-chunks
  const float* src; unsigned short* dst; int sloc; int dloc;
  if      (i4 < 102400)  { src = q;     dst = q16;    sloc = i4;           dloc = sloc; }
  else if (i4 < 2191360) { src = value; dst = v16;    sloc = i4 - 102400;  dloc = sloc; }
  else if (i4 < 2584576) { src = Woff;  dst = Wq16;   sloc = i4 - 2191360; dloc = sloc; }
  else if (i4 < 2781184) { src = Wattn; dst = Wq16;   sloc = i4 - 2584576; dloc = sloc + 393216; }
  else if (i4 < 2797568) { src = Wv;    dst = Wv16;   sloc = i4 - 2781184; dloc = sloc; }
  else                   { src = Wout;  dst = Wout16; sloc = i4 - 2797568; dloc = sloc; }
  float4 x = ((const float4*)src)[sloc];
  ushort4 hh;
  hh.x = f2h(x.x); hh.y = f2h(x.y); hh.z = f2h(x.z); hh.w = f2h(x.w);
  ((ushort4*)dst)[dloc] = hh;
}

// ---------------------------------------------------------------------------
// Merged fp16 MFMA GEMM. Round-24 change: tile 128x128 -> 64x64 (BK=128
// kept) — the EXACT verified gemmh0 structure, applied to gemm23.
//   grid 1446 -> 5640 blocks; LDS 64 -> 32 KB => 5 blocks/CU co-resident
//   (was 2): each block's 2 vmcnt drains overlap with 4 other blocks'
//   stage/MFMA phases — cross-block TLP that the 128-sq tile lacked.
// Cost: 2x panel re-reads (~370 MB from L2 ≈ 15 µs of 34.5 TB/s) and a
// lower per-block MFMA:drain ratio; the bet is residency x overlap wins.
// Ladder so far (measured): BK64=74*, BK128@128sq=59.5, BK256=89, noLDS=81.
//   blocks [0, 3600):    offs/attn GEMM — 25 m-tiles x 144 n-tiles,
//                        XCD-chunked bijective: 3600 = 8 x 450, 18 nt/XCD
//                        (A 800KB + 18x64-col B panel 590KB ~ 1.4MB in L2)
//   blocks [3600, 5640): val GEMM — 510 m-tiles x 4 n-tiles
// ---------------------------------------------------------------------------
__global__ __launch_bounds__(256) void gemm23_kernel(
    const unsigned short* __restrict__ q16, const unsigned short* __restrict__ Wq16,
    const unsigned short* __restrict__ v16, const unsigned short* __restrict__ Wv16,
    const float* __restrict__ boff, const float* __restrict__ battn,
    unsigned short* __restrict__ offs16, unsigned short* __restrict__ attn16,
    unsigned short* __restrict__ val_t) {
  __shared__ unsigned short LA0[64 * 32], LA1[64 * 32], LA2[64 * 32], LA3[64 * 32];
  __shared__ unsigned short LB0[64 * 32], LB1[64 * 32], LB2[64 * 32], LB3[64 * 32];

  const int bid = blockIdx.x;
  const unsigned short *A, *B;
  int M, bm, bn;
  bool isVal;
  if (bid < 3600) {          // offs/attn: XCD x owns n-tiles [18x, 18x+18)
    int x = bid & 7, i = bid >> 3;          // i in [0,450)
    int nt = x * 18 + (i % 18), mt = i / 18;  // nt in [0,144), mt in [0,25)
    A = q16;  B = Wq16;  M = QQ;
    bn = nt * 64;  bm = mt * 64;  isVal = false;
  } else {                   // val: 4 n-tiles x 510 m-tiles
    int b2 = bid - 3600;
    A = v16;  B = Wv16;  M = NVv * SLENs;
    bn = (b2 & 3) * 64;  bm = (b2 >> 2) * 64;  isVal = true;
  }
  const int K = EMB;

  const int tid = threadIdx.x;
  const int lane = tid & 63, w = tid >> 6;
  const int wm = (w & 1) * 32, wn = (w >> 1) * 32;
  const int l16 = lane & 15, quad = lane >> 4;

  // one dma16 round covers a full 64x32 slice: 256 chunks of 8 halfs
  const int r0 = tid >> 2, s0 = (tid & 3) * 8;
  const size_t a0 = (size_t)min(bm + r0, M - 1) * K + s0;
  const size_t b0o = (size_t)(bn + r0) * K + s0;
  const int l0 = tid * 8;

  f32x4 acc[2][2] = {};

#pragma unroll
  for (int k0 = 0; k0 < K; k0 += 128) {
    dma16(&A[a0 + k0],       &LA0[l0]);
    dma16(&A[a0 + k0 + 32],  &LA1[l0]);
    dma16(&A[a0 + k0 + 64],  &LA2[l0]);
    dma16(&A[a0 + k0 + 96],  &LA3[l0]);
    dma16(&B[b0o + k0],      &LB0[l0]);
    dma16(&B[b0o + k0 + 32], &LB1[l0]);
    dma16(&B[b0o + k0 + 64], &LB2[l0]);
    dma16(&B[b0o + k0 + 96], &LB3[l0]);
    __syncthreads();
    GEMM_COMPUTE2(LA0, LB0);
    GEMM_COMPUTE2(LA1, LB1);
    GEMM_COMPUTE2(LA2, LB2);
    GEMM_COMPUTE2(LA3, LB3);
    __syncthreads();
  }

  // epilogue: C/D layout col(n)=lane&15, row(m)=quad*4+reg  [m89-verified]
#pragma unroll
  for (int j = 0; j < 2; ++j) {
    int n = bn + wn + j * 16 + l16;
    float bv = 0.f;
    bool dotanh = false;
    if (!isVal) {
      if (n < A_OFF) { bv = boff[n]; dotanh = true; }
      else bv = battn[n - A_OFF];
    }
#pragma unroll
    for (int i = 0; i < 2; ++i) {
      int mbase = bm + wm + i * 16 + quad * 4;
#pragma unroll
      for (int reg = 0; reg < 4; ++reg) {
        int m = mbase + reg;
        if (m >= M) continue;
        float c = acc[i][j][reg] + bv;
        if (isVal) {   // fp16 permuted store: m=(v*SLEN+s), n=(h*32+d)
          int vv = m / SLENs;
          int s = m - vv * SLENs;
          int hh2 = n >> 5, dd = n & 31;
          val_t[((size_t)(vv * 8 + hh2) * SLENs + s) * 32 + dd] = f2h(c);
        } else if (dotanh) {
          float t = __expf(2.f * c);
          c = 1.f - 2.f / (t + 1.f);
          offs16[(size_t)m * A_OFF + n] = f2h(c);
        } else {
          attn16[(size_t)m * A_ATTN + (n - A_OFF)] = f2h(c);
        }
      }
    }
  }
}

// ---------------------------------------------------------------------------
// fp16 MFMA GEMM, MODE 0 only (final out = out_pre @ Wout.T, f32 store).
// VERIFIED r11 form: 64x64 tiles (100 blocks), BK=128 four static slice
// pairs (32 KB LDS), two drains per block. stage->sync->compute only.
// ---------------------------------------------------------------------------
__global__ __launch_bounds__(256) void gemmh0_kernel(
    const unsigned short* __restrict__ A, const unsigned short* __restrict__ B,
    float* __restrict__ C, int M, int N, int K) {
  __shared__ unsigned short LA0[64 * 32], LA1[64 * 32], LA2[64 * 32], LA3[64 * 32];
  __shared__ unsigned short LB0[64 * 32], LB1[64 * 32], LB2[64 * 32], LB3[64 * 32];

  const int tid = threadIdx.x;
  const int bm = blockIdx.y * 64, bn = blockIdx.x * 64;
  const int lane = tid & 63, w = tid >> 6;
  const int wm = (w & 1) * 32, wn = (w >> 1) * 32;
  const int l16 = lane & 15, quad = lane >> 4;

  // one dma16 round covers a full 64x32 slice: 256 chunks of 8 halfs
  const int r0 = tid >> 2, s0 = (tid & 3) * 8;
  const size_t a0 = (size_t)min(bm + r0, M - 1) * K + s0;
  const size_t b0o = (size_t)(bn + r0) * K + s0;
  const int l0 = tid * 8;

  f32x4 acc[2][2] = {};

#pragma unroll
  for (int k0 = 0; k0 < K; k0 += 128) {
    dma16(&A[a0 + k0],       &LA0[l0]);
    dma16(&A[a0 + k0 + 32],  &LA1[l0]);
    dma16(&A[a0 + k0 + 64],  &LA2[l0]);
    dma16(&A[a0 + k0 + 96],  &LA3[l0]);
    dma16(&B[b0o + k0],      &LB0[l0]);
    dma16(&B[b0o + k0 + 32], &LB1[l0]);
    dma16(&B[b0o + k0 + 64], &LB2[l0]);
    dma16(&B[b0o + k0 + 96], &LB3[l0]);
    __syncthreads();
    GEMM_COMPUTE2(LA0, LB0);
    GEMM_COMPUTE2(LA1, LB1);
    GEMM_COMPUTE2(LA2, LB2);
    GEMM_COMPUTE2(LA3, LB3);
    __syncthreads();
  }

#pragma unroll
  for (int j = 0; j < 2; ++j) {
    int n = bn + wn + j * 16 + l16;
#pragma unroll
    for (int i = 0; i < 2; ++i) {
      int mbase = bm + wm + i * 16 + quad * 4;
#pragma unroll
      for (int reg = 0; reg < 4; ++reg) {
        int m = mbase + reg;
        if (m >= M) continue;
        C[(size_t)m * N + n] = acc[i][j][reg];
      }
    }
  }
}

// ---------------------------------------------------------------------------
// Fused softmax + record build + sampling — VERIFIED round-7 form
// (256 threads, 4 waves, Lrec[4][384], grid QQ*NH/4). Declared done at
// ~60 µs: occupancy levers null (rounds 1/8), MLP levers null (round 6),
// VALU lever captured (round 5). L1 line-rate floor ~32 µs + issue stream.
// ---------------------------------------------------------------------------
__global__ __launch_bounds__(256) void sample_kernel(
    const float* __restrict__ ref, const unsigned short* __restrict__ offs16,
    const unsigned short* __restrict__ attn16,
    const unsigned short* __restrict__ val_t,
    unsigned short* __restrict__ op16) {
  __shared__ int4 Lrec[4][384];

  const int h   = blockIdx.x & 7;
  const int qt  = blockIdx.x >> 3;
  const int wid = threadIdx.x >> 6;
  const int lane = threadIdx.x & 63;
  const int q   = qt * 4 + wid;
  const int row = q * 8 + h;

  {
    const unsigned short* ap = attn16 + (size_t)row * 384;
    float vals[6];
    float mx = -1e30f;
#pragma unroll
    for (int i = 0; i < 6; ++i) { vals[i] = h2f(ap[lane + i * 64]); mx = fmaxf(mx, vals[i]); }
#pragma unroll
    for (int o = 32; o > 0; o >>= 1) mx = fmaxf(mx, __shfl_xor(mx, o, 64));
    float s = 0.f;
#pragma unroll
    for (int i = 0; i < 6; ++i) { vals[i] = __expf(vals[i] - mx); s += vals[i]; }
#pragma unroll
    for (int o = 32; o > 0; o >>= 1) s += __shfl_xor(s, o, 64);
    const float inv = 1.0f / s;

    const int l = (lane >> 4) & 3;
    const int z = lane & 3;
    const int Wl = 64 >> l;
    const int start = (l == 0) ? 0 : (l == 1 ? 4096 : (l == 2 ? 5120 : 5376));
    const float sc = 0.5f * (float)(Wl - 1);
    const unsigned int* op = (const unsigned int*)offs16 + (size_t)row * 384;
    const float* rq = ref + (size_t)q * (NVv * 4 * 4 * 2);

#pragma unroll 1
    for (int v = 0; v < 6; ++v) {
      int j = v * 64 + lane;
      float w = vals[v] * inv;
      unsigned int oxy = op[j];
      float ox = h2f((unsigned short)(oxy & 0xFFFF));
      float oy = h2f((unsigned short)(oxy >> 16));
      const float* rp = rq + ((v * 4 + l) * 4 + z) * 2;
      float rx = rp[0], ry = rp[1];
      float x = fminf(1.f, fmaxf(-1.f, rx + ox));
      float y = fminf(1.f, fmaxf(-1.f, ry + oy));
      float xp = (x + 1.f) * sc, yp = (y + 1.f) * sc;
      float x0f = floorf(xp), y0f = floorf(yp);
      int x0 = (int)x0f, y0 = (int)y0f;
      float wx = xp - x0f, wy = yp - y0f;
      unsigned i00 = (unsigned)(start + y0 * Wl + x0);
      unsigned dxe = (x0 + 1 < Wl) ? 1u : 0u;
      unsigned dye = (y0 + 1 < Wl) ? (unsigned)Wl : 0u;
      unsigned i10 = i00 + dye;
      float wxw = wx * w, wmx = w - wxw;
      float w01 = wxw * (1.f - wy), w11 = wxw * wy;
      float w00 = wmx * (1.f - wy), w10 = wmx * wy;
      Lrec[wid][j] = make_int4(
          (int)(i00         | ((unsigned)f2h(w00) << 16)),
          (int)((i00 + dxe) | ((unsigned)f2h(w01) << 16)),
          (int)(i10         | ((unsigned)f2h(w10) << 16)),
          (int)((i10 + dxe) | ((unsigned)f2h(w11) << 16)));
    }
  }
  // no __syncthreads: each wave consumes only its own Lrec slice

  const int cb  = (lane >> 2) & 3;
  const int e16 = (lane & 3) << 4;
  const int r   = lane >> 4;

  const unsigned* Lw = (const unsigned*)&Lrec[wid][0];

  float acc[8] = {};

#pragma unroll 1
  for (int v = 0; v < 6; ++v) {
    const char* sb = (const char*)val_t + (size_t)(v * 8 + h) * (SLENs * 64);
    const int rbase = v * 64 + r;
#pragma unroll 8
    for (int t = 0; t < 16; ++t) {
      int ri = rbase + t * 4;
      unsigned u = Lw[ri * 4 + cb];
      int voff = ((int)(u & 0xFFFFu) << 6) + e16;
      uint4 d = *(const uint4*)(sb + voff);
      FMAMIX_LO(acc[0], d.x, u);  FMAMIX_HI(acc[1], d.x, u);
      FMAMIX_LO(acc[2], d.y, u);  FMAMIX_HI(acc[3], d.y, u);
      FMAMIX_LO(acc[4], d.z, u);  FMAMIX_HI(acc[5], d.z, u);
      FMAMIX_LO(acc[6], d.w, u);  FMAMIX_HI(acc[7], d.w, u);
    }
  }

#pragma unroll
  for (int m = 4; m <= 32; m <<= 1)
#pragma unroll
    for (int j = 0; j < 8; ++j) acc[j] += __shfl_xor(acc[j], m, 64);

  if (lane < 4) {
    int off = q * EMB + h * 32 + lane * 8;
    ushort4 h0, h1;
    h0.x = f2h(acc[0]); h0.y = f2h(acc[1]); h0.z = f2h(acc[2]); h0.w = f2h(acc[3]);
    h1.x = f2h(acc[4]); h1.y = f2h(acc[5]); h1.z = f2h(acc[6]); h1.w = f2h(acc[7]);
    *(ushort4*)&op16[off] = h0;  *(ushort4*)&op16[off + 4] = h1;
  }
}

// ---------------------------------------------------------------------------
extern "C" void kernel_launch(void* const* d_in, const int* in_sizes, int n_in,
                              void* d_out, int out_size, void* d_ws, size_t ws_size,
                              hipStream_t stream) {
  const float* queries    = (const float*)d_in[0];
  const float* ref_points = (const float*)d_in[1];
  const float* value      = (const float*)d_in[2];
  const float* Wv    = (const float*)d_in[4];
  const float* Woff  = (const float*)d_in[5];
  const float* boff  = (const float*)d_in[6];
  const float* Wattn = (const float*)d_in[7];
  const float* battn = (const float*)d_in[8];
  const float* Wout  = (const float*)d_in[9];
  float* out = (float*)d_out;

  // ws layout, byte offsets — total 69.5 MB.
  char* W = (char*)d_ws;
  unsigned short* offs16 = (unsigned short*)(W + 0);         // 19,660,800
  unsigned short* attn16 = (unsigned short*)(W + 19660800);  //  9,830,400
  unsigned short* val_t  = (unsigned short*)(W + 29491200);  // 16,711,680 (fp16)
  unsigned short* q16    = (unsigned short*)(W + 46202880);  //    819,200
  unsigned short* v16    = (unsigned short*)(W + 47022080);  // 16,711,680
  unsigned short* Wq16   = (unsigned short*)(W + 63733760);  //  4,718,592 (Woff||Wattn)
  unsigned short* Wv16   = (unsigned short*)(W + 68452352);  //    131,072
  unsigned short* Wout16 = (unsigned short*)(W + 68583424);  //    131,072
  unsigned short* op16   = (unsigned short*)(W + 68714496);  //    819,200

  dim3 blk(256);

  // 1. convert all GEMM operands to fp16 (single-pass)
  split_h_kernel<<<10992, blk, 0, stream>>>(
      queries, value, Woff, Wattn, Wv, Wout, q16, v16, Wq16, Wv16, Wout16);
  // 2. merged offs/attn GEMM (3600 blocks, XCD-chunked) + val GEMM (2040)
  gemm23_kernel<<<5640, blk, 0, stream>>>(
      q16, Wq16, v16, Wv16, boff, battn, offs16, attn16, val_t);
  // 3. fused softmax + record build + sampling -> out_pre fp16
  sample_kernel<<<QQ * NHh / 4, blk, 0, stream>>>(
      ref_points, offs16, attn16, val_t, op16);
  // 4. out = out_pre @ Wout.T (fp16 in, fp32 out) — 64x64 tiles, 100 blocks
  gemmh0_kernel<<<dim3(EMB / 64, QQ / 64), blk, 0, stream>>>(
      op16, Wout16, out, QQ, EMB, EMB);
}